// Round 1
// baseline (1581.310 us; speedup 1.0000x reference)
//
#include <hip/hip_runtime.h>
#include <hip/hip_bf16.h>

#define T_TOKENS 8192
#define D_DIM 1024
#define H_DIM 4096
#define E_NUM 8
#define CAP 8192
#define BM 128
#define BN 128
#define BK 64
#define LDT 72   // 64 + 8 ushort pad: 144B row stride breaks power-of-2 bank aliasing

typedef short bf16x8 __attribute__((ext_vector_type(8)));
typedef float f32x4 __attribute__((ext_vector_type(4)));

__device__ inline unsigned short f2bf(float f) {
    union { float f; unsigned int u; } v; v.f = f;
    unsigned int u = v.u;
    return (unsigned short)((u + 0x7fffu + ((u >> 16) & 1u)) >> 16);  // RNE
}

__device__ inline float gelu_tanh(float v) {
    float c = 0.7978845608028654f * (v + 0.044715f * v * v * v);
    float t = 1.0f - 2.0f / (__expf(2.0f * c) + 1.0f);   // tanh(c)
    return 0.5f * v * (1.0f + t);
}

// XOR swizzle for B tile stored as Bs[n][k]: spreads the k-column scatter
// writes (and frag reads) across banks. Keeps 8-runs of k contiguous.
__device__ inline int bswz(int n, int k) { return k ^ (((n >> 2) & 7) << 3); }

// ---------------- gate: logits (fp64 acc), top-2, softmax, routing lists ---
__global__ __launch_bounds__(256) void gate_kernel(const float* __restrict__ x,
                                                   const float* __restrict__ gw,
                                                   int* __restrict__ cnt,
                                                   int* __restrict__ tok,
                                                   float* __restrict__ cf) {
    int lane = threadIdx.x & 63;
    int t = blockIdx.x * 4 + (threadIdx.x >> 6);   // one wave per token
    const float* xr = x + (size_t)t * D_DIM;
    double acc[E_NUM];
#pragma unroll
    for (int e = 0; e < E_NUM; ++e) acc[e] = 0.0;
    for (int d = lane; d < D_DIM; d += 64) {
        double xv = (double)xr[d];
        const float* g = gw + (size_t)d * E_NUM;
#pragma unroll
        for (int e = 0; e < E_NUM; ++e) acc[e] += xv * (double)g[e];
    }
#pragma unroll
    for (int e = 0; e < E_NUM; ++e) {
        double v = acc[e];
#pragma unroll
        for (int off = 32; off >= 1; off >>= 1) v += __shfl_xor(v, off);
        acc[e] = v;
    }
    if (lane == 0) {
        int s0 = 0;
#pragma unroll
        for (int e = 1; e < E_NUM; ++e) if (acc[e] > acc[s0]) s0 = e;   // first max (tie->low idx)
        int s1 = -1;
#pragma unroll
        for (int e = 0; e < E_NUM; ++e) if (e != s0 && (s1 < 0 || acc[e] > acc[s1])) s1 = e;
        float l0 = (float)acc[s0], l1 = (float)acc[s1];  // l0 >= l1
        float p1 = __expf(l1 - l0);
        float inv = 1.0f / (1.0f + p1);
        int q0 = atomicAdd(&cnt[s0], 1);
        tok[s0 * CAP + q0] = t;  cf[s0 * CAP + q0] = inv;
        int q1 = atomicAdd(&cnt[s1], 1);
        tok[s1 * CAP + q1] = t;  cf[s1 * CAP + q1] = p1 * inv;
    }
}

// ---------------- GEMM1: H = gelu(Xg @ w1[e] + b1[e]) -> bf16 Hbuf ---------
__global__ __launch_bounds__(256) void gemm1_kernel(const float* __restrict__ x,
                                                    const float* __restrict__ w1,
                                                    const float* __restrict__ b1,
                                                    const int* __restrict__ cnt,
                                                    const int* __restrict__ tok,
                                                    unsigned short* __restrict__ Hbuf) {
    int e = blockIdx.z;
    int ne = cnt[e];
    int bm0 = blockIdx.x * BM;
    if (bm0 >= ne) return;
    int n0 = blockIdx.y * BN;
    int offs = 0;
#pragma unroll
    for (int i = 0; i < E_NUM; ++i) offs += (i < e) ? cnt[i] : 0;

    __shared__ __align__(16) unsigned short As[BM][LDT];  // As[m][k]
    __shared__ __align__(16) unsigned short Bs[BN][LDT];  // Bs[n][k] (swizzled k)
    __shared__ int s_tok[BM];

    int tid = threadIdx.x;
    if (tid < BM) {
        int gi = min(bm0 + tid, ne - 1);
        s_tok[tid] = tok[e * CAP + gi];
    }

    const float* w1e = w1 + (size_t)e * D_DIM * H_DIM;

    f32x4 acc[4][4];
#pragma unroll
    for (int i = 0; i < 4; ++i)
#pragma unroll
        for (int j = 0; j < 4; ++j) { f32x4 z = {0.f, 0.f, 0.f, 0.f}; acc[i][j] = z; }

    int lane = tid & 63;
    int wv = tid >> 6;
    int wr = (wv >> 1) * 64, wc = (wv & 1) * 64;
    int lm = lane & 15, lk = lane >> 4;
    int ar = tid >> 4, ac4 = tid & 15;    // A stage: 16 rows x 16 float4
    int bk = tid >> 5, bn4 = tid & 31;    // B stage: 8 k x 32 float4(n)

    for (int kb = 0; kb < D_DIM / BK; ++kb) {
        int k0 = kb * BK;
        __syncthreads();
        // A: gather token rows of x, fp32 -> bf16
#pragma unroll
        for (int p = 0; p < 8; ++p) {
            int row = ar + p * 16;
            const float4 v = *(const float4*)(x + (size_t)s_tok[row] * D_DIM + k0 + ac4 * 4);
            ushort4 u; u.x = f2bf(v.x); u.y = f2bf(v.y); u.z = f2bf(v.z); u.w = f2bf(v.w);
            *(ushort4*)&As[row][ac4 * 4] = u;
        }
        // B: w1e[k][n] -> Bs[n][k] (transpose + convert, swizzled)
#pragma unroll
        for (int p = 0; p < 8; ++p) {
            int k = bk + p * 8;
            const float4 v = *(const float4*)(w1e + (size_t)(k0 + k) * H_DIM + n0 + bn4 * 4);
            Bs[bn4 * 4 + 0][bswz(bn4 * 4 + 0, k)] = f2bf(v.x);
            Bs[bn4 * 4 + 1][bswz(bn4 * 4 + 1, k)] = f2bf(v.y);
            Bs[bn4 * 4 + 2][bswz(bn4 * 4 + 2, k)] = f2bf(v.z);
            Bs[bn4 * 4 + 3][bswz(bn4 * 4 + 3, k)] = f2bf(v.w);
        }
        __syncthreads();
#pragma unroll
        for (int ks = 0; ks < 2; ++ks) {
            bf16x8 a[4], b[4];
            int kbase = ks * 32 + lk * 8;
#pragma unroll
            for (int f = 0; f < 4; ++f)
                a[f] = *(const bf16x8*)&As[wr + f * 16 + lm][kbase];
#pragma unroll
            for (int f = 0; f < 4; ++f) {
                int n = wc + f * 16 + lm;
                b[f] = *(const bf16x8*)&Bs[n][bswz(n, kbase)];
            }
#pragma unroll
            for (int i = 0; i < 4; ++i)
#pragma unroll
                for (int j = 0; j < 4; ++j)
                    acc[i][j] = __builtin_amdgcn_mfma_f32_16x16x32_bf16(a[i], b[j], acc[i][j], 0, 0, 0);
        }
    }
    const float* b1e = b1 + (size_t)e * H_DIM;
#pragma unroll
    for (int i = 0; i < 4; ++i) {
#pragma unroll
        for (int r = 0; r < 4; ++r) {
            int row = wr + i * 16 + lk * 4 + r;
            int gr = bm0 + row;
            if (gr >= ne) continue;
            size_t rb = (size_t)(offs + gr) * H_DIM;
#pragma unroll
            for (int j = 0; j < 4; ++j) {
                int gn = n0 + wc + j * 16 + lm;
                float v = acc[i][j][r] + b1e[gn];
                Hbuf[rb + gn] = f2bf(gelu_tanh(v));
            }
        }
    }
}

// ---------------- GEMM2: out[tok] += coef * (H @ w2[e] + b2[e]) ------------
__global__ __launch_bounds__(256) void gemm2_kernel(const unsigned short* __restrict__ Hbuf,
                                                    const float* __restrict__ w2,
                                                    const float* __restrict__ b2,
                                                    const int* __restrict__ cnt,
                                                    const int* __restrict__ tok,
                                                    const float* __restrict__ cf,
                                                    float* __restrict__ out) {
    int e = blockIdx.z;
    int ne = cnt[e];
    int bm0 = blockIdx.x * BM;
    if (bm0 >= ne) return;
    int n0 = blockIdx.y * BN;
    int offs = 0;
#pragma unroll
    for (int i = 0; i < E_NUM; ++i) offs += (i < e) ? cnt[i] : 0;

    __shared__ __align__(16) unsigned short As[BM][LDT];
    __shared__ __align__(16) unsigned short Bs[BN][LDT];
    __shared__ int s_tok[BM];
    __shared__ float s_cf[BM];

    int tid = threadIdx.x;
    if (tid < BM) {
        int gi = min(bm0 + tid, ne - 1);
        s_tok[tid] = tok[e * CAP + gi];
        s_cf[tid] = cf[e * CAP + gi];
    }

    const float* w2e = w2 + (size_t)e * H_DIM * D_DIM;

    f32x4 acc[4][4];
#pragma unroll
    for (int i = 0; i < 4; ++i)
#pragma unroll
        for (int j = 0; j < 4; ++j) { f32x4 z = {0.f, 0.f, 0.f, 0.f}; acc[i][j] = z; }

    int lane = tid & 63;
    int wv = tid >> 6;
    int wr = (wv >> 1) * 64, wc = (wv & 1) * 64;
    int lm = lane & 15, lk = lane >> 4;
    int ar = tid >> 4, ac4 = tid & 15;
    int bk = tid >> 5, bn4 = tid & 31;

    for (int kb = 0; kb < H_DIM / BK; ++kb) {
        int k0 = kb * BK;
        __syncthreads();
        // A: contiguous bf16 rows of Hbuf (expert-compacted)
#pragma unroll
        for (int p = 0; p < 8; ++p) {
            int row = ar + p * 16;
            size_t src = (size_t)(offs + min(bm0 + row, ne - 1)) * H_DIM + k0 + ac4 * 4;
            *(ushort4*)&As[row][ac4 * 4] = *(const ushort4*)(Hbuf + src);
        }
        // B: w2e[k][n] -> Bs[n][k]
#pragma unroll
        for (int p = 0; p < 8; ++p) {
            int k = bk + p * 8;
            const float4 v = *(const float4*)(w2e + (size_t)(k0 + k) * D_DIM + n0 + bn4 * 4);
            Bs[bn4 * 4 + 0][bswz(bn4 * 4 + 0, k)] = f2bf(v.x);
            Bs[bn4 * 4 + 1][bswz(bn4 * 4 + 1, k)] = f2bf(v.y);
            Bs[bn4 * 4 + 2][bswz(bn4 * 4 + 2, k)] = f2bf(v.z);
            Bs[bn4 * 4 + 3][bswz(bn4 * 4 + 3, k)] = f2bf(v.w);
        }
        __syncthreads();
#pragma unroll
        for (int ks = 0; ks < 2; ++ks) {
            bf16x8 a[4], b[4];
            int kbase = ks * 32 + lk * 8;
#pragma unroll
            for (int f = 0; f < 4; ++f)
                a[f] = *(const bf16x8*)&As[wr + f * 16 + lm][kbase];
#pragma unroll
            for (int f = 0; f < 4; ++f) {
                int n = wc + f * 16 + lm;
                b[f] = *(const bf16x8*)&Bs[n][bswz(n, kbase)];
            }
#pragma unroll
            for (int i = 0; i < 4; ++i)
#pragma unroll
                for (int j = 0; j < 4; ++j)
                    acc[i][j] = __builtin_amdgcn_mfma_f32_16x16x32_bf16(a[i], b[j], acc[i][j], 0, 0, 0);
        }
    }
    const float* b2e = b2 + (size_t)e * D_DIM;
#pragma unroll
    for (int i = 0; i < 4; ++i) {
#pragma unroll
        for (int r = 0; r < 4; ++r) {
            int row = wr + i * 16 + lk * 4 + r;
            int gr = bm0 + row;
            if (gr >= ne) continue;
            int tk = s_tok[row];
            float w = s_cf[row];
#pragma unroll
            for (int j = 0; j < 4; ++j) {
                int gn = n0 + wc + j * 16 + lm;
                float y = acc[i][j][r] + b2e[gn];
                atomicAdd(&out[(size_t)tk * D_DIM + gn], w * y);
            }
        }
    }
}

extern "C" void kernel_launch(void* const* d_in, const int* in_sizes, int n_in,
                              void* d_out, int out_size, void* d_ws, size_t ws_size,
                              hipStream_t stream) {
    const float* x  = (const float*)d_in[0];
    const float* gw = (const float*)d_in[1];
    const float* w1 = (const float*)d_in[2];
    const float* b1 = (const float*)d_in[3];
    const float* w2 = (const float*)d_in[4];
    const float* b2 = (const float*)d_in[5];
    float* out = (float*)d_out;

    char* ws = (char*)d_ws;
    int*   cnt  = (int*)ws;                                   // 8 ints
    int*   tok  = (int*)(ws + 256);                           // E*CAP ints
    float* cff  = (float*)(ws + 256 + E_NUM * CAP * 4);       // E*CAP floats
    unsigned short* Hbuf = (unsigned short*)(ws + 256 + 2 * E_NUM * CAP * 4);

    size_t need = 256 + (size_t)2 * E_NUM * CAP * 4 + (size_t)2 * T_TOKENS * H_DIM * 2;
    if (ws_size < need) return;   // signals ws too small (out stays poisoned)

    hipMemsetAsync(cnt, 0, E_NUM * sizeof(int), stream);
    hipMemsetAsync(out, 0, (size_t)out_size * sizeof(float), stream);

    gate_kernel<<<T_TOKENS / 4, 256, 0, stream>>>(x, gw, cnt, tok, cff);

    dim3 g1(CAP / BM, H_DIM / BN, E_NUM);
    gemm1_kernel<<<g1, 256, 0, stream>>>(x, w1, b1, cnt, tok, Hbuf);

    dim3 g2(CAP / BM, D_DIM / BN, E_NUM);
    gemm2_kernel<<<g2, 256, 0, stream>>>(Hbuf, w2, b2, cnt, tok, cff, out);
}

// Round 2
// 1240.887 us; speedup vs baseline: 1.2743x; 1.2743x over previous
//
#include <hip/hip_runtime.h>
#include <hip/hip_bf16.h>

#define T_TOKENS 8192
#define D_DIM 1024
#define H_DIM 4096
#define E_NUM 8
#define CAP 8192
#define BM 128
#define BN 128
#define BK 64
#define LDT 72   // fallback-path pad

typedef short bf16x8 __attribute__((ext_vector_type(8)));
typedef float f32x4 __attribute__((ext_vector_type(4)));
typedef unsigned short u16x8 __attribute__((ext_vector_type(8)));

__device__ inline unsigned short f2bf(float f) {
    union { float f; unsigned int u; } v; v.f = f;
    unsigned int u = v.u;
    return (unsigned short)((u + 0x7fffu + ((u >> 16) & 1u)) >> 16);  // RNE
}

__device__ inline float gelu_tanh(float v) {
    float c = 0.7978845608028654f * (v + 0.044715f * v * v * v);
    float t = 1.0f - 2.0f / (__expf(2.0f * c) + 1.0f);   // tanh(c)
    return 0.5f * v * (1.0f + t);
}

// async global->LDS, 16B per lane; lds base must be wave-uniform (HW adds lane*16)
__device__ inline void gld_lds16(const unsigned short* g, unsigned short* lds) {
    __builtin_amdgcn_global_load_lds(
        (const __attribute__((address_space(1))) void*)g,
        (__attribute__((address_space(3))) void*)lds, 16, 0, 0);
}

// ---------------- gate: logits (fp64 acc), top-2, softmax, routing lists ---
__global__ __launch_bounds__(256) void gate_kernel(const float* __restrict__ x,
                                                   const float* __restrict__ gw,
                                                   int* __restrict__ cnt,
                                                   int* __restrict__ tok,
                                                   float* __restrict__ cf) {
    int lane = threadIdx.x & 63;
    int t = blockIdx.x * 4 + (threadIdx.x >> 6);
    const float* xr = x + (size_t)t * D_DIM;
    double acc[E_NUM];
#pragma unroll
    for (int e = 0; e < E_NUM; ++e) acc[e] = 0.0;
    for (int d = lane; d < D_DIM; d += 64) {
        double xv = (double)xr[d];
        const float* g = gw + (size_t)d * E_NUM;
#pragma unroll
        for (int e = 0; e < E_NUM; ++e) acc[e] += xv * (double)g[e];
    }
#pragma unroll
    for (int e = 0; e < E_NUM; ++e) {
        double v = acc[e];
#pragma unroll
        for (int off = 32; off >= 1; off >>= 1) v += __shfl_xor(v, off);
        acc[e] = v;
    }
    if (lane == 0) {
        int s0 = 0;
#pragma unroll
        for (int e = 1; e < E_NUM; ++e) if (acc[e] > acc[s0]) s0 = e;
        int s1 = -1;
#pragma unroll
        for (int e = 0; e < E_NUM; ++e) if (e != s0 && (s1 < 0 || acc[e] > acc[s1])) s1 = e;
        float l0 = (float)acc[s0], l1 = (float)acc[s1];
        float p1 = __expf(l1 - l0);
        float inv = 1.0f / (1.0f + p1);
        int q0 = atomicAdd(&cnt[s0], 1);
        tok[s0 * CAP + q0] = t;  cf[s0 * CAP + q0] = inv;
        int q1 = atomicAdd(&cnt[s1], 1);
        tok[s1 * CAP + q1] = t;  cf[s1 * CAP + q1] = p1 * inv;
    }
}

// ---------------- prepass: x fp32 -> bf16 ----------------------------------
__global__ __launch_bounds__(256) void cvt_x_kernel(const float* __restrict__ x,
                                                    unsigned short* __restrict__ xb) {
    size_t i = ((size_t)blockIdx.x * 256 + threadIdx.x) * 8;
    float4 v0 = *(const float4*)(x + i);
    float4 v1 = *(const float4*)(x + i + 4);
    u16x8 u;
    u[0] = f2bf(v0.x); u[1] = f2bf(v0.y); u[2] = f2bf(v0.z); u[3] = f2bf(v0.w);
    u[4] = f2bf(v1.x); u[5] = f2bf(v1.y); u[6] = f2bf(v1.z); u[7] = f2bf(v1.w);
    *(u16x8*)(xb + i) = u;
}

// ---------------- prepass: w [E][K][N] fp32 -> wt [E][N][K] bf16 -----------
// tile: 64 k x 128 n, 256 threads
__global__ __launch_bounds__(256) void trw_kernel(const float* __restrict__ w,
                                                  unsigned short* __restrict__ wt,
                                                  int K, int N) {
    __shared__ float t[64][132];
    int e = blockIdx.z;
    int k0 = blockIdx.y * 64;
    int n0 = blockIdx.x * 128;
    const float* we = w + (size_t)e * K * N;
    unsigned short* wte = wt + (size_t)e * K * N;
    int tid = threadIdx.x;
    int rk = tid >> 5;
    int rn = (tid & 31) * 4;
#pragma unroll
    for (int p = 0; p < 8; ++p) {
        int k = rk + p * 8;
        float4 v = *(const float4*)(we + (size_t)(k0 + k) * N + n0 + rn);
        t[k][rn] = v.x; t[k][rn + 1] = v.y; t[k][rn + 2] = v.z; t[k][rn + 3] = v.w;
    }
    __syncthreads();
    int n = tid >> 1;
    int kc = (tid & 1) * 32;
    unsigned short* dst = wte + (size_t)(n0 + n) * K + k0 + kc;
#pragma unroll
    for (int c8 = 0; c8 < 4; ++c8) {
        u16x8 u;
#pragma unroll
        for (int c = 0; c < 8; ++c) u[c] = f2bf(t[kc + c8 * 8 + c][n]);
        *(u16x8*)(dst + c8 * 8) = u;
    }
}

// ================= FAST PATH: m97-structure GEMMs ==========================
// 128x128x64 tile, 4 waves, global_load_lds(16B) staging, linear LDS.

__global__ __launch_bounds__(256) void gemm1_fast(const unsigned short* __restrict__ xb,
                                                  const unsigned short* __restrict__ w1t,
                                                  const float* __restrict__ b1,
                                                  const int* __restrict__ cnt,
                                                  const int* __restrict__ tok,
                                                  unsigned short* __restrict__ Hbuf) {
    int e = blockIdx.z;
    int ne = cnt[e];
    int bm0 = blockIdx.x * BM;
    if (bm0 >= ne) return;
    int n0 = blockIdx.y * BN;
    int offs = 0;
#pragma unroll
    for (int i = 0; i < E_NUM; ++i) offs += (i < e) ? cnt[i] : 0;

    __shared__ __align__(16) unsigned short As[BM][BK];
    __shared__ __align__(16) unsigned short Bs[BN][BK];
    __shared__ int s_tok[BM];

    int tid = threadIdx.x, lane = tid & 63, wv = tid >> 6;
    if (tid < BM) s_tok[tid] = tok[e * CAP + min(bm0 + tid, ne - 1)];

    int wr = (wv >> 1) * 64, wc = (wv & 1) * 64;
    int lm = lane & 15, lk = lane >> 4;
    int lrow8 = lane >> 3;          // row within 8-row staging group
    int lk8 = (lane & 7) * 8;       // k element offset (16B chunk)

    const unsigned short* w1e = w1t + (size_t)e * H_DIM * D_DIM;  // [n][k]

    f32x4 acc[4][4];
#pragma unroll
    for (int i = 0; i < 4; ++i)
#pragma unroll
        for (int j = 0; j < 4; ++j) { f32x4 z = {0.f, 0.f, 0.f, 0.f}; acc[i][j] = z; }

    for (int kb = 0; kb < D_DIM / BK; ++kb) {
        int k0 = kb * BK;
        __syncthreads();
#pragma unroll
        for (int i = 0; i < 4; ++i) {
            int r0 = (i * 4 + wv) * 8;
            const unsigned short* g = xb + (size_t)s_tok[r0 + lrow8] * D_DIM + k0 + lk8;
            gld_lds16(g, &As[r0][0]);
        }
#pragma unroll
        for (int i = 0; i < 4; ++i) {
            int r0 = (i * 4 + wv) * 8;
            const unsigned short* g = w1e + (size_t)(n0 + r0 + lrow8) * D_DIM + k0 + lk8;
            gld_lds16(g, &Bs[r0][0]);
        }
        __syncthreads();
#pragma unroll
        for (int ks = 0; ks < 2; ++ks) {
            bf16x8 a[4], b[4];
            int kbase = ks * 32 + lk * 8;
#pragma unroll
            for (int f = 0; f < 4; ++f) a[f] = *(const bf16x8*)&As[wr + f * 16 + lm][kbase];
#pragma unroll
            for (int f = 0; f < 4; ++f) b[f] = *(const bf16x8*)&Bs[wc + f * 16 + lm][kbase];
#pragma unroll
            for (int i = 0; i < 4; ++i)
#pragma unroll
                for (int j = 0; j < 4; ++j)
                    acc[i][j] = __builtin_amdgcn_mfma_f32_16x16x32_bf16(a[i], b[j], acc[i][j], 0, 0, 0);
        }
    }
    const float* b1e = b1 + (size_t)e * H_DIM;
#pragma unroll
    for (int i = 0; i < 4; ++i) {
#pragma unroll
        for (int r = 0; r < 4; ++r) {
            int row = wr + i * 16 + lk * 4 + r;
            int gr = bm0 + row;
            if (gr >= ne) continue;
            size_t rb = (size_t)(offs + gr) * H_DIM;
#pragma unroll
            for (int j = 0; j < 4; ++j) {
                int gn = n0 + wc + j * 16 + lm;
                float v = acc[i][j][r] + b1e[gn];
                Hbuf[rb + gn] = f2bf(gelu_tanh(v));
            }
        }
    }
}

__global__ __launch_bounds__(256) void gemm2_fast(const unsigned short* __restrict__ Hbuf,
                                                  const unsigned short* __restrict__ w2t,
                                                  const float* __restrict__ b2,
                                                  const int* __restrict__ cnt,
                                                  const int* __restrict__ tok,
                                                  const float* __restrict__ cf,
                                                  float* __restrict__ out) {
    int e = blockIdx.z;
    int ne = cnt[e];
    int bm0 = blockIdx.x * BM;
    if (bm0 >= ne) return;
    int n0 = blockIdx.y * BN;
    int offs = 0;
#pragma unroll
    for (int i = 0; i < E_NUM; ++i) offs += (i < e) ? cnt[i] : 0;

    __shared__ __align__(16) unsigned short As[BM][BK];
    __shared__ __align__(16) unsigned short Bs[BN][BK];
    __shared__ int s_tok[BM];
    __shared__ float s_cf[BM];

    int tid = threadIdx.x, lane = tid & 63, wv = tid >> 6;
    if (tid < BM) {
        int gi = min(bm0 + tid, ne - 1);
        s_tok[tid] = tok[e * CAP + gi];
        s_cf[tid] = cf[e * CAP + gi];
    }

    int wr = (wv >> 1) * 64, wc = (wv & 1) * 64;
    int lm = lane & 15, lk = lane >> 4;
    int lrow8 = lane >> 3;
    int lk8 = (lane & 7) * 8;

    const unsigned short* w2e = w2t + (size_t)e * H_DIM * D_DIM;  // [n][k]

    f32x4 acc[4][4];
#pragma unroll
    for (int i = 0; i < 4; ++i)
#pragma unroll
        for (int j = 0; j < 4; ++j) { f32x4 z = {0.f, 0.f, 0.f, 0.f}; acc[i][j] = z; }

    for (int kb = 0; kb < H_DIM / BK; ++kb) {
        int k0 = kb * BK;
        __syncthreads();
#pragma unroll
        for (int i = 0; i < 4; ++i) {
            int r0 = (i * 4 + wv) * 8;
            size_t src = (size_t)(offs + min(bm0 + r0 + lrow8, ne - 1)) * H_DIM + k0 + lk8;
            gld_lds16(Hbuf + src, &As[r0][0]);
        }
#pragma unroll
        for (int i = 0; i < 4; ++i) {
            int r0 = (i * 4 + wv) * 8;
            const unsigned short* g = w2e + (size_t)(n0 + r0 + lrow8) * H_DIM + k0 + lk8;
            gld_lds16(g, &Bs[r0][0]);
        }
        __syncthreads();
#pragma unroll
        for (int ks = 0; ks < 2; ++ks) {
            bf16x8 a[4], b[4];
            int kbase = ks * 32 + lk * 8;
#pragma unroll
            for (int f = 0; f < 4; ++f) a[f] = *(const bf16x8*)&As[wr + f * 16 + lm][kbase];
#pragma unroll
            for (int f = 0; f < 4; ++f) b[f] = *(const bf16x8*)&Bs[wc + f * 16 + lm][kbase];
#pragma unroll
            for (int i = 0; i < 4; ++i)
#pragma unroll
                for (int j = 0; j < 4; ++j)
                    acc[i][j] = __builtin_amdgcn_mfma_f32_16x16x32_bf16(a[i], b[j], acc[i][j], 0, 0, 0);
        }
    }
    const float* b2e = b2 + (size_t)e * D_DIM;
#pragma unroll
    for (int i = 0; i < 4; ++i) {
#pragma unroll
        for (int r = 0; r < 4; ++r) {
            int row = wr + i * 16 + lk * 4 + r;
            int gr = bm0 + row;
            if (gr >= ne) continue;
            int tk = s_tok[row];
            float w = s_cf[row];
#pragma unroll
            for (int j = 0; j < 4; ++j) {
                int gn = n0 + wc + j * 16 + lm;
                float y = acc[i][j][r] + b2e[gn];
                atomicAdd(&out[(size_t)tk * D_DIM + gn], w * y);
            }
        }
    }
}

// ================= FALLBACK PATH (round-1 kernels, known-pass) =============
__device__ inline int bswz(int n, int k) { return k ^ (((n >> 2) & 7) << 3); }

__global__ __launch_bounds__(256) void gemm1_slow(const float* __restrict__ x,
                                                  const float* __restrict__ w1,
                                                  const float* __restrict__ b1,
                                                  const int* __restrict__ cnt,
                                                  const int* __restrict__ tok,
                                                  unsigned short* __restrict__ Hbuf) {
    int e = blockIdx.z;
    int ne = cnt[e];
    int bm0 = blockIdx.x * BM;
    if (bm0 >= ne) return;
    int n0 = blockIdx.y * BN;
    int offs = 0;
#pragma unroll
    for (int i = 0; i < E_NUM; ++i) offs += (i < e) ? cnt[i] : 0;
    __shared__ __align__(16) unsigned short As[BM][LDT];
    __shared__ __align__(16) unsigned short Bs[BN][LDT];
    __shared__ int s_tok[BM];
    int tid = threadIdx.x;
    if (tid < BM) s_tok[tid] = tok[e * CAP + min(bm0 + tid, ne - 1)];
    const float* w1e = w1 + (size_t)e * D_DIM * H_DIM;
    f32x4 acc[4][4];
#pragma unroll
    for (int i = 0; i < 4; ++i)
#pragma unroll
        for (int j = 0; j < 4; ++j) { f32x4 z = {0.f, 0.f, 0.f, 0.f}; acc[i][j] = z; }
    int lane = tid & 63, wv = tid >> 6;
    int wr = (wv >> 1) * 64, wc = (wv & 1) * 64;
    int lm = lane & 15, lk = lane >> 4;
    int ar = tid >> 4, ac4 = tid & 15;
    int bk = tid >> 5, bn4 = tid & 31;
    for (int kb = 0; kb < D_DIM / BK; ++kb) {
        int k0 = kb * BK;
        __syncthreads();
#pragma unroll
        for (int p = 0; p < 8; ++p) {
            int row = ar + p * 16;
            const float4 v = *(const float4*)(x + (size_t)s_tok[row] * D_DIM + k0 + ac4 * 4);
            ushort4 u; u.x = f2bf(v.x); u.y = f2bf(v.y); u.z = f2bf(v.z); u.w = f2bf(v.w);
            *(ushort4*)&As[row][ac4 * 4] = u;
        }
#pragma unroll
        for (int p = 0; p < 8; ++p) {
            int k = bk + p * 8;
            const float4 v = *(const float4*)(w1e + (size_t)(k0 + k) * H_DIM + n0 + bn4 * 4);
            Bs[bn4 * 4 + 0][bswz(bn4 * 4 + 0, k)] = f2bf(v.x);
            Bs[bn4 * 4 + 1][bswz(bn4 * 4 + 1, k)] = f2bf(v.y);
            Bs[bn4 * 4 + 2][bswz(bn4 * 4 + 2, k)] = f2bf(v.z);
            Bs[bn4 * 4 + 3][bswz(bn4 * 4 + 3, k)] = f2bf(v.w);
        }
        __syncthreads();
#pragma unroll
        for (int ks = 0; ks < 2; ++ks) {
            bf16x8 a[4], b[4];
            int kbase = ks * 32 + lk * 8;
#pragma unroll
            for (int f = 0; f < 4; ++f) a[f] = *(const bf16x8*)&As[wr + f * 16 + lm][kbase];
#pragma unroll
            for (int f = 0; f < 4; ++f) { int n = wc + f * 16 + lm; b[f] = *(const bf16x8*)&Bs[n][bswz(n, kbase)]; }
#pragma unroll
            for (int i = 0; i < 4; ++i)
#pragma unroll
                for (int j = 0; j < 4; ++j)
                    acc[i][j] = __builtin_amdgcn_mfma_f32_16x16x32_bf16(a[i], b[j], acc[i][j], 0, 0, 0);
        }
    }
    const float* b1e = b1 + (size_t)e * H_DIM;
#pragma unroll
    for (int i = 0; i < 4; ++i) {
#pragma unroll
        for (int r = 0; r < 4; ++r) {
            int row = wr + i * 16 + lk * 4 + r;
            int gr = bm0 + row;
            if (gr >= ne) continue;
            size_t rb = (size_t)(offs + gr) * H_DIM;
#pragma unroll
            for (int j = 0; j < 4; ++j) {
                int gn = n0 + wc + j * 16 + lm;
                float v = acc[i][j][r] + b1e[gn];
                Hbuf[rb + gn] = f2bf(gelu_tanh(v));
            }
        }
    }
}

__global__ __launch_bounds__(256) void gemm2_slow(const unsigned short* __restrict__ Hbuf,
                                                  const float* __restrict__ w2,
                                                  const float* __restrict__ b2,
                                                  const int* __restrict__ cnt,
                                                  const int* __restrict__ tok,
                                                  const float* __restrict__ cf,
                                                  float* __restrict__ out) {
    int e = blockIdx.z;
    int ne = cnt[e];
    int bm0 = blockIdx.x * BM;
    if (bm0 >= ne) return;
    int n0 = blockIdx.y * BN;
    int offs = 0;
#pragma unroll
    for (int i = 0; i < E_NUM; ++i) offs += (i < e) ? cnt[i] : 0;
    __shared__ __align__(16) unsigned short As[BM][LDT];
    __shared__ __align__(16) unsigned short Bs[BN][LDT];
    __shared__ int s_tok[BM];
    __shared__ float s_cf[BM];
    int tid = threadIdx.x;
    if (tid < BM) {
        int gi = min(bm0 + tid, ne - 1);
        s_tok[tid] = tok[e * CAP + gi];
        s_cf[tid] = cf[e * CAP + gi];
    }
    const float* w2e = w2 + (size_t)e * H_DIM * D_DIM;
    f32x4 acc[4][4];
#pragma unroll
    for (int i = 0; i < 4; ++i)
#pragma unroll
        for (int j = 0; j < 4; ++j) { f32x4 z = {0.f, 0.f, 0.f, 0.f}; acc[i][j] = z; }
    int lane = tid & 63, wv = tid >> 6;
    int wr = (wv >> 1) * 64, wc = (wv & 1) * 64;
    int lm = lane & 15, lk = lane >> 4;
    int ar = tid >> 4, ac4 = tid & 15;
    int bk = tid >> 5, bn4 = tid & 31;
    for (int kb = 0; kb < H_DIM / BK; ++kb) {
        int k0 = kb * BK;
        __syncthreads();
#pragma unroll
        for (int p = 0; p < 8; ++p) {
            int row = ar + p * 16;
            size_t src = (size_t)(offs + min(bm0 + row, ne - 1)) * H_DIM + k0 + ac4 * 4;
            *(ushort4*)&As[row][ac4 * 4] = *(const ushort4*)(Hbuf + src);
        }
#pragma unroll
        for (int p = 0; p < 8; ++p) {
            int k = bk + p * 8;
            const float4 v = *(const float4*)(w2e + (size_t)(k0 + k) * D_DIM + n0 + bn4 * 4);
            Bs[bn4 * 4 + 0][bswz(bn4 * 4 + 0, k)] = f2bf(v.x);
            Bs[bn4 * 4 + 1][bswz(bn4 * 4 + 1, k)] = f2bf(v.y);
            Bs[bn4 * 4 + 2][bswz(bn4 * 4 + 2, k)] = f2bf(v.z);
            Bs[bn4 * 4 + 3][bswz(bn4 * 4 + 3, k)] = f2bf(v.w);
        }
        __syncthreads();
#pragma unroll
        for (int ks = 0; ks < 2; ++ks) {
            bf16x8 a[4], b[4];
            int kbase = ks * 32 + lk * 8;
#pragma unroll
            for (int f = 0; f < 4; ++f) a[f] = *(const bf16x8*)&As[wr + f * 16 + lm][kbase];
#pragma unroll
            for (int f = 0; f < 4; ++f) { int n = wc + f * 16 + lm; b[f] = *(const bf16x8*)&Bs[n][bswz(n, kbase)]; }
#pragma unroll
            for (int i = 0; i < 4; ++i)
#pragma unroll
                for (int j = 0; j < 4; ++j)
                    acc[i][j] = __builtin_amdgcn_mfma_f32_16x16x32_bf16(a[i], b[j], acc[i][j], 0, 0, 0);
        }
    }
    const float* b2e = b2 + (size_t)e * D_DIM;
#pragma unroll
    for (int i = 0; i < 4; ++i) {
#pragma unroll
        for (int r = 0; r < 4; ++r) {
            int row = wr + i * 16 + lk * 4 + r;
            int gr = bm0 + row;
            if (gr >= ne) continue;
            int tk = s_tok[row];
            float w = s_cf[row];
#pragma unroll
            for (int j = 0; j < 4; ++j) {
                int gn = n0 + wc + j * 16 + lm;
                float y = acc[i][j][r] + b2e[gn];
                atomicAdd(&out[(size_t)tk * D_DIM + gn], w * y);
            }
        }
    }
}

extern "C" void kernel_launch(void* const* d_in, const int* in_sizes, int n_in,
                              void* d_out, int out_size, void* d_ws, size_t ws_size,
                              hipStream_t stream) {
    const float* x  = (const float*)d_in[0];
    const float* gw = (const float*)d_in[1];
    const float* w1 = (const float*)d_in[2];
    const float* b1 = (const float*)d_in[3];
    const float* w2 = (const float*)d_in[4];
    const float* b2 = (const float*)d_in[5];
    float* out = (float*)d_out;

    char* ws = (char*)d_ws;
    const size_t SZ_ROUTE = 256 + (size_t)2 * E_NUM * CAP * 4;             // cnt+tok+cf
    const size_t SZ_XB    = (size_t)T_TOKENS * D_DIM * 2;                  // 16.8 MB
    const size_t SZ_W     = (size_t)E_NUM * D_DIM * H_DIM * 2;             // 67.1 MB each
    const size_t SZ_H     = (size_t)2 * T_TOKENS * H_DIM * 2;              // 134.2 MB

    int*   cnt = (int*)ws;
    int*   tok = (int*)(ws + 256);
    float* cff = (float*)(ws + 256 + E_NUM * CAP * 4);

    size_t need_fast = SZ_ROUTE + SZ_XB + 2 * SZ_W + SZ_H;
    size_t need_slow = SZ_ROUTE + SZ_H;

    hipMemsetAsync(cnt, 0, E_NUM * sizeof(int), stream);
    hipMemsetAsync(out, 0, (size_t)out_size * sizeof(float), stream);
    gate_kernel<<<T_TOKENS / 4, 256, 0, stream>>>(x, gw, cnt, tok, cff);

    if (ws_size >= need_fast) {
        unsigned short* xb   = (unsigned short*)(ws + SZ_ROUTE);
        unsigned short* w1t  = (unsigned short*)(ws + SZ_ROUTE + SZ_XB);
        unsigned short* w2t  = (unsigned short*)(ws + SZ_ROUTE + SZ_XB + SZ_W);
        unsigned short* Hbuf = (unsigned short*)(ws + SZ_ROUTE + SZ_XB + 2 * SZ_W);

        cvt_x_kernel<<<T_TOKENS * D_DIM / 8 / 256, 256, 0, stream>>>(x, xb);
        dim3 gt1(H_DIM / 128, D_DIM / 64, E_NUM);
        trw_kernel<<<gt1, 256, 0, stream>>>(w1, w1t, D_DIM, H_DIM);
        dim3 gt2(D_DIM / 128, H_DIM / 64, E_NUM);
        trw_kernel<<<gt2, 256, 0, stream>>>(w2, w2t, H_DIM, D_DIM);

        dim3 g1(CAP / BM, H_DIM / BN, E_NUM);
        gemm1_fast<<<g1, 256, 0, stream>>>(xb, w1t, b1, cnt, tok, Hbuf);
        dim3 g2(CAP / BM, D_DIM / BN, E_NUM);
        gemm2_fast<<<g2, 256, 0, stream>>>(Hbuf, w2t, b2, cnt, tok, cff, out);
    } else if (ws_size >= need_slow) {
        unsigned short* Hbuf = (unsigned short*)(ws + SZ_ROUTE);
        dim3 g1(CAP / BM, H_DIM / BN, E_NUM);
        gemm1_slow<<<g1, 256, 0, stream>>>(x, w1, b1, cnt, tok, Hbuf);
        dim3 g2(CAP / BM, D_DIM / BN, E_NUM);
        gemm2_slow<<<g2, 256, 0, stream>>>(Hbuf, w2, b2, cnt, tok, cff, out);
    }
    // if neither fits, out stays zeroed -> loud failure signals ws too small
}